// Round 9
// baseline (189.511 us; speedup 1.0000x reference)
//
#include <hip/hip_runtime.h>

// ---------------------------------------------------------------------------
// Gate_16501264351574: conv3x3(256ch -> 64 experts) + sigmoid + top8 + softmax
//   x: [16,256,64,64] f32, gate_w: [64,256,3,3] f32, bias: [64] f32
// out (flat f32): weights [16,8,64,64] | indices-as-f32 [16,8,64,64] | counts[64]
//
// R17: more, smaller, de-phased blocks on the R14 structure (best main).
// R16 showed wave-privacy alone loses (occupancy+traffic); the real deficit
// is independent instruction streams per SIMD: grid 1024 = 4 identical
// blocks/CU, phase-aligned stalls. Now block = (b, r, ph): 32 positions x
// 64 experts, 128 threads (2 waves, eh 0/1), grid 2048 = 8 blocks/CU.
//   - A slab 2x8KB block-shared (no duplication), XOR-swizzled (R15),
//     staged via 4 uniform global_load_lds per thread (pad granules -> dead
//     LDS region so vmcnt counts match across waves).
//   - B: 6-deep register rotation, counted vmcnt(18)+lgkm(0) barrier per
//     chunk (R14), barrier group now 2 waves.
//   - chunk-phase rotation: block starts K at chunk (blk>>8)&7 -> the 8
//     co-resident blocks/CU touch different xT/wB regions each step.
// prep: reverted to R14's prep_all2 (best measured).
// Fallback (ws too small): R9 structure verbatim.
// ---------------------------------------------------------------------------

typedef _Float16 half8 __attribute__((ext_vector_type(8)));
typedef __attribute__((ext_vector_type(4))) float f32x4;

#define LOG2E 1.44269504f

__device__ __forceinline__ unsigned short f2h_bits(float f) {
    _Float16 h = (_Float16)f;                  // v_cvt_f16_f32, RNE
    unsigned short b;
    __builtin_memcpy(&b, &h, 2);
    return b;
}

constexpr int WB_U4 = 8 * 9 * 4 * 64;          // 18432 uint4 = 294912 B
constexpr size_t XT_BYTES = (size_t)16 * 66 * 8 * 66 * 32 * 2;  // 35,684,352
constexpr size_t WS_NEED  = XT_BYTES + (size_t)WB_U4 * 16 + 262144;

#define GLOAD16(gp, lp)                                                    \
    __builtin_amdgcn_global_load_lds(                                      \
        (const __attribute__((address_space(1))) void*)(gp),               \
        (__attribute__((address_space(3))) void*)(lp), 16, 0, 0)

// ===========================================================================
// FAST PATH
// ===========================================================================

// prep_all2 (R14 verbatim): [0,4096) interior, [4096,4226) border zero,
// [4226,4298) wB fragments (+counts zero).
constexpr int NB_INT = 4096, NB_BOR = 130, NB_WB = 72;
constexpr int PREP_GRID = NB_INT + NB_BOR + NB_WB;   // 4298

__global__ __launch_bounds__(256) void prep_all2(
    const float* __restrict__ x, const float* __restrict__ gw,
    _Float16* __restrict__ xT, unsigned short* __restrict__ wB,
    float* __restrict__ out) {
    const int blk = blockIdx.x, tid = threadIdx.x;
    if (blk < NB_INT) {
        int gid = blk * 256 + tid;
        int w = gid & 63, c16 = (gid >> 6) & 15, h = (gid >> 10) & 63, b = gid >> 16;
        int c0 = c16 * 16;
        const float* src = x + ((b * 256 + c0) * 64 + h) * 64 + w;
        float v[16];
#pragma unroll
        for (int j = 0; j < 16; ++j) v[j] = src[j * 4096];
        uint4 p0, p1;
        p0.x = (unsigned)f2h_bits(v[0])  | ((unsigned)f2h_bits(v[1])  << 16);
        p0.y = (unsigned)f2h_bits(v[2])  | ((unsigned)f2h_bits(v[3])  << 16);
        p0.z = (unsigned)f2h_bits(v[4])  | ((unsigned)f2h_bits(v[5])  << 16);
        p0.w = (unsigned)f2h_bits(v[6])  | ((unsigned)f2h_bits(v[7])  << 16);
        p1.x = (unsigned)f2h_bits(v[8])  | ((unsigned)f2h_bits(v[9])  << 16);
        p1.y = (unsigned)f2h_bits(v[10]) | ((unsigned)f2h_bits(v[11]) << 16);
        p1.z = (unsigned)f2h_bits(v[12]) | ((unsigned)f2h_bits(v[13]) << 16);
        p1.w = (unsigned)f2h_bits(v[14]) | ((unsigned)f2h_bits(v[15]) << 16);
        int q = c16 >> 1;
        size_t idx = ((((size_t)b * 66 + h + 1) * 8 + q) * 66 + (w + 1)) * 32
                     + (c16 & 1) * 16;
        uint4* dst = (uint4*)(xT + idx);
        dst[0] = p0; dst[1] = p1;
    } else if (blk < NB_INT + NB_BOR) {
        int t = (blk - NB_INT) * 256 + tid;    // < 33280 exactly
        int q = t & 7, site = t >> 3;          // site < 4160
        int sb = site / 260, s = site - sb * 260;
        int hp, wp;
        if (s < 132) { hp = (s >= 66) ? 65 : 0; wp = (s >= 66) ? (s - 66) : s; }
        else         { int s2 = s - 132; hp = 1 + (s2 >> 1); wp = (s2 & 1) * 65; }
        uint4 z = {0u, 0u, 0u, 0u};
        size_t idx = ((((size_t)sb * 66 + hp) * 8 + q) * 66 + wp) * 32;
        uint4* dst = (uint4*)(xT + idx);
#pragma unroll
        for (int k = 0; k < 4; ++k) dst[k] = z;
    } else {
        int wblk = blk - (NB_INT + NB_BOR);
        if (wblk == 0 && tid < 64) out[1048576 + tid] = 0.f;
        int g = wblk * 256 + tid;              // < WB_U4 exactly
        int lane = g & 63;
        int nt   = (g >> 6) & 3;
        int rest = g >> 8;                     // q*9 + t
        int t = rest % 9, q = rest / 9;
        int e  = nt * 16 + (lane & 15);
        int c0 = q * 32 + (lane >> 4) * 8;
        unsigned short o[8];
#pragma unroll
        for (int j = 0; j < 8; ++j)
            o[j] = f2h_bits(gw[(e * 256 + c0 + j) * 9 + t]);
        uint4 pk;
        pk.x = (unsigned)o[0] | ((unsigned)o[1] << 16);
        pk.y = (unsigned)o[2] | ((unsigned)o[3] << 16);
        pk.z = (unsigned)o[4] | ((unsigned)o[5] << 16);
        pk.w = (unsigned)o[6] | ((unsigned)o[7] << 16);
        ((uint4*)wB)[g] = pk;
    }
}

// ---------------------------------------------------------------------------
// gate_main6: grid 2048, block = (b=blk&15, r=(blk>>4)&63, ph=blk>>10),
// 128 threads = 2 waves (eh = wave id). Wave = 32 pos x 32 exp.
// LDS: slab 2 x 8192 B (A dbuf; 408 granules + 104 pad), scf aliases.
// Chunk order rotated by phase = (blk>>8)&7.
// ---------------------------------------------------------------------------
constexpr int SSTR6 = 68;                      // fp32 score row stride
constexpr int HALF6 = 8192;                    // slab half bytes

__global__ __launch_bounds__(128, 4) void gate_main6(
    const _Float16* __restrict__ xT, const float* __restrict__ bias,
    const unsigned short* __restrict__ wB, float* __restrict__ out) {
    __shared__ uint4 smem4[2 * HALF6 / 16];    // 16384 B (scf aliases)
    __shared__ float bias_s[64];
    __shared__ int   hist[64];
    char* smem = (char*)smem4;

    const int tid  = threadIdx.x;
    const int lane = tid & 63;
    const int eh   = tid >> 6;                 // wave id = expert half
    const int blk  = blockIdx.x;
    const int b    = blk & 15;
    const int r    = (blk >> 4) & 63;          // output row
    const int ph   = blk >> 10;                // column half
    const int phase = (blk >> 8) & 7;          // chunk rotation

    if (tid < 64) { bias_s[tid] = bias[tid]; hist[tid] = 0; }

    // ---- staging: 408 granules = [seg 3][site 34][c8slot 4] x 16B, plus
    // 104 pad granules (dead LDS [6528,8192)). 4 uniform rounds x 128 thr.
    // Source c8 XOR-swizzled: c8 = c8slot ^ ((s>>1)&3) (both-sides rule).
    const _Float16* srcB[4];
    int loff[4];
#pragma unroll
    for (int i = 0; i < 4; ++i) {
        int T = tid + i * 128;
        loff[i] = T * 16;
        if (T < 408) {
            int st = T >> 2, c8s = T & 3;
            int seg = st / 34, s = st - seg * 34;
            int c8 = c8s ^ ((s >> 1) & 3);
            srcB[i] = xT + ((size_t)((b * 66 + r + seg) * 8)) * 2112
                         + (ph * 32 + s) * 32 + c8 * 8;
        } else {
            srcB[i] = xT;                      // pad: valid src, dead dest
        }
    }
    auto STAGE = [&](int q, int HB) {          // 4 x global_load_lds / thread
#pragma unroll
        for (int i = 0; i < 4; ++i)
            GLOAD16(srcB[i] + q * 2112, smem + loff[i] + HB);
    };

    // ---- A read bases (ds_read_b128), swizzled; block-shared slab --------
    const char* aB[3];
#pragma unroll
    for (int kw = 0; kw < 3; ++kw) {
        int s  = (lane & 15) + kw;
        int c8 = (lane >> 4) ^ ((s >> 1) & 3);
        aB[kw] = smem + s * 64 + c8 * 16;
    }

    half8 Aa[3][2];
    uint4 Bb[6][2];
    f32x4 acc[2][2];
#pragma unroll
    for (int mt = 0; mt < 2; ++mt)
#pragma unroll
        for (int nt = 0; nt < 2; ++nt) acc[mt][nt] = (f32x4){0.f, 0.f, 0.f, 0.f};

    auto LDA = [&](int kh, int kw, int slot, int HB) {   // literals only
        Aa[slot][0] = *(const half8*)(aB[kw] + HB + kh * 2176);
        Aa[slot][1] = *(const half8*)(aB[kw] + HB + kh * 2176 + 1024);
    };
    const char* wBeh = (const char*)wB + eh * 2048 + lane * 16;
    auto LDBo = [&](const char* p, int off, int slot) {
        Bb[slot][0] = *(const uint4*)(p + off);
        Bb[slot][1] = *(const uint4*)(p + off + 1024);
    };
    auto MT = [&](int as, int bs) {
#pragma unroll
        for (int nt = 0; nt < 2; ++nt) {
            half8 bfr;
            __builtin_memcpy(&bfr, &Bb[bs][nt], 16);
#pragma unroll
            for (int m = 0; m < 2; ++m)
                acc[m][nt] = __builtin_amdgcn_mfma_f32_16x16x32_f16(
                    Aa[as][m], bfr, acc[m][nt], 0, 0, 0);
        }
    };
    auto SB = []() { __builtin_amdgcn_sched_barrier(0); };

    // ---- prologue: stage chunk 'phase' into half0, B taps 0-5 ------------
    const char* p0 = wBeh + phase * 36864;
    STAGE(phase, 0);
    LDBo(p0, 0, 0); LDBo(p0, 4096, 1); LDBo(p0, 8192, 2);
    LDBo(p0, 12288, 3); LDBo(p0, 16384, 4); LDBo(p0, 20480, 5);
    SB();
    asm volatile("s_waitcnt vmcnt(12)" ::: "memory");   // staging landed
    __builtin_amdgcn_s_barrier();
    SB();
    const char* pC = p0 + 24576;               // current-chunk tap6

    // ---- K loop: 4 x (even chunk HB=0, odd chunk HB=HALF6), rotated ------
#pragma unroll 1
    for (int ii = 0; ii < 4; ++ii) {
        // ===== even chunk i=2ii: read half0, stage qn -> half1 ============
        int qn = (phase + 2 * ii + 1) & 7;
        const char* pN = wBeh + qn * 36864;
        STAGE(qn, HALF6);
        LDA(0, 0, 0, 0); LDA(0, 1, 1, 0); LDA(0, 2, 2, 0); SB();
        MT(0, 0); LDA(1, 0, 0, 0); LDBo(pC, 0, 0);     SB();
        MT(1, 1); LDA(1, 1, 1, 0); LDBo(pC, 4096, 1);  SB();
        MT(2, 2); LDA(1, 2, 2, 0); LDBo(pC, 8192, 2);  SB();
        MT(0, 3); LDA(2, 0, 0, 0); LDBo(pN, 0, 3);     SB();
        MT(1, 4); LDA(2, 1, 1, 0); LDBo(pN, 4096, 4);  SB();
        MT(2, 5); LDA(2, 2, 2, 0); LDBo(pN, 8192, 5);  SB();
        MT(0, 0); LDBo(pN, 12288, 0); SB();
        MT(1, 1); LDBo(pN, 16384, 1); SB();
        MT(2, 2); LDBo(pN, 20480, 2); SB();
        SB();
        asm volatile("s_waitcnt vmcnt(18) lgkmcnt(0)" ::: "memory");
        __builtin_amdgcn_s_barrier();
        SB();
        pC = pN + 24576;
        // ===== odd chunk i=2ii+1: read half1, stage qn2 -> half0 ==========
        int qn2 = (phase + 2 * ii + 2) & 7;
        const char* pN2 = wBeh + qn2 * 36864;
        if (ii < 3) STAGE(qn2, 0);
        LDA(0, 0, 0, HALF6); LDA(0, 1, 1, HALF6); LDA(0, 2, 2, HALF6); SB();
        MT(0, 3); LDA(1, 0, 0, HALF6); LDBo(pC, 0, 3);     SB();
        MT(1, 4); LDA(1, 1, 1, HALF6); LDBo(pC, 4096, 4);  SB();
        MT(2, 5); LDA(1, 2, 2, HALF6); LDBo(pC, 8192, 5);  SB();
        MT(0, 0); LDA(2, 0, 0, HALF6); LDBo(pN2, 0, 0);    SB();
        MT(1, 1); LDA(2, 1, 1, HALF6); LDBo(pN2, 4096, 1); SB();
        MT(2, 2); LDA(2, 2, 2, HALF6); LDBo(pN2, 8192, 2); SB();
        MT(0, 3); LDBo(pN2, 12288, 3); SB();
        MT(1, 4); LDBo(pN2, 16384, 4); SB();
        MT(2, 5); LDBo(pN2, 20480, 5); SB();
        if (ii < 3) {
            SB();
            asm volatile("s_waitcnt vmcnt(18) lgkmcnt(0)" ::: "memory");
            __builtin_amdgcn_s_barrier();
            SB();
        }
        pC = pN2 + 24576;
    }
    __syncthreads();                           // full drain before scf alias

    // ---- epilogue: sigmoid -> fp32 scores in LDS (aliases slab) -----------
    float* scf = (float*)smem4;                // [32][68] f32 = 8704 B
#pragma unroll
    for (int mt = 0; mt < 2; ++mt)
#pragma unroll
        for (int nt = 0; nt < 2; ++nt)
#pragma unroll
            for (int rr = 0; rr < 4; ++rr) {
                float v = acc[mt][nt][rr];
                float s = 1.f / (1.f + __builtin_amdgcn_exp2f(-v * LOG2E));
                int p = mt * 16 + ((lane >> 4) << 2) + rr;   // local pos 0..31
                int e = eh * 32 + nt * 16 + (lane & 15);
                scf[p * SSTR6 + e] = s;
            }
    __syncthreads();

    if (tid < 32) {
        const float* row = scf + tid * SSTR6;
        float tv[8];
        int   ti[8];
#pragma unroll
        for (int k = 0; k < 8; ++k) { tv[k] = -3.0e38f; ti[k] = 0; }
#pragma unroll
        for (int j4 = 0; j4 < 16; ++j4) {
            f32x4 blkv = *(const f32x4*)(row + j4 * 4);
#pragma unroll
            for (int j = 0; j < 4; ++j) {
                int   e  = j4 * 4 + j;
                float bs = blkv[j] + bias_s[e];
                if (bs > tv[7]) {
                    tv[7] = bs; ti[7] = e;
#pragma unroll
                    for (int k = 7; k > 0; --k) {
                        float fa = tv[k - 1], fb = tv[k];
                        int   ia = ti[k - 1], ib = ti[k];
                        bool  sw = fb > fa;
                        tv[k - 1] = sw ? fb : fa; tv[k] = sw ? fa : fb;
                        ti[k - 1] = sw ? ib : ia; ti[k] = sw ? ia : ib;
                    }
                }
            }
        }
        float u[8], mx = -3.0e38f;
#pragma unroll
        for (int k = 0; k < 8; ++k) { u[k] = tv[k] - bias_s[ti[k]]; mx = fmaxf(mx, u[k]); }
        float ex[8], sum = 0.f;
#pragma unroll
        for (int k = 0; k < 8; ++k) { ex[k] = __builtin_amdgcn_exp2f((u[k] - mx) * LOG2E); sum += ex[k]; }
        float inv = 1.f / sum;

        int obase = b * 32768 + r * 64 + ph * 32 + tid;   // [b][k][h=r][w]
#pragma unroll
        for (int k = 0; k < 8; ++k) {
            out[obase + k * 4096]          = ex[k] * inv;
            out[524288 + obase + k * 4096] = (float)ti[k];
            atomicAdd(&hist[ti[k]], 1);
        }
    }
    __syncthreads();
    if (tid < 64) atomicAdd(out + 1048576 + tid, (float)hist[tid]);
}

// ===========================================================================
// FALLBACK PATH (R9 verbatim)
// ===========================================================================

__global__ __launch_bounds__(256) void gate_prep(const float* __restrict__ gw,
                                                 unsigned short* __restrict__ wB,
                                                 float* __restrict__ out) {
    int g = blockIdx.x * 256 + threadIdx.x;
    if (blockIdx.x == 0 && threadIdx.x < 64) out[1048576 + threadIdx.x] = 0.f;
    if (g >= WB_U4) return;
    int lane = g & 63;
    int nt   = (g >> 6) & 3;
    int rest = g >> 8;
    int t = rest % 9, q = rest / 9;
    int e  = nt * 16 + (lane & 15);
    int c0 = q * 32 + (lane >> 4) * 8;
    unsigned short o[8];
#pragma unroll
    for (int j = 0; j < 8; ++j)
        o[j] = f2h_bits(gw[(e * 256 + c0 + j) * 9 + t]);
    uint4 pk;
    pk.x = (unsigned)o[0] | ((unsigned)o[1] << 16);
    pk.y = (unsigned)o[2] | ((unsigned)o[3] << 16);
    pk.z = (unsigned)o[4] | ((unsigned)o[5] << 16);
    pk.w = (unsigned)o[6] | ((unsigned)o[7] << 16);
    ((uint4*)wB)[g] = pk;
}

constexpr int CSTR = 40;
constexpr int SLAB = 3 * 66 * CSTR;
constexpr int SSTR = 68;

__global__ __launch_bounds__(256, 4) void gate_main_fb(
    const float* __restrict__ x, const float* __restrict__ bias,
    const unsigned short* __restrict__ wB, float* __restrict__ out) {
    __shared__ unsigned short xs[2 * SLAB];
    __shared__ float bias_s[64];
    __shared__ int   hist[64];

    const int tid  = threadIdx.x;
    const int lane = tid & 63;
    const int rw   = tid >> 6;
    const int blk  = blockIdx.x;
    const int b    = blk & 15;
    const int r    = blk >> 4;

    if (tid < 64) { bias_s[tid] = bias[tid]; hist[tid] = 0; }
    {
        uint4 z = {0u, 0u, 0u, 0u};
        uint4* p = (uint4*)xs;
#pragma unroll
        for (int i = 0; i < 8; ++i) {
            int idx = tid + i * 256;
            if (idx < 2 * SLAB / 8) p[idx] = z;
        }
    }

    bool tOk[4];
    int  tSrc[4], tDst[4];
#pragma unroll
    for (int i = 0; i < 4; ++i) {
        int T = tid + i * 256;
        bool ex = (T < 792);
        int chh = T / 198, s = T - chh * 198;
        int row2 = s / 66, wp = s - row2 * 66;
        int gr = r - 1 + row2, gwc = wp - 1;
        tOk[i]  = ex && (gr >= 0) && (gr < 64) && (gwc >= 0) && (gwc < 64);
        tSrc[i] = ((b * 256 + chh * 8) * 64 + gr) * 64 + gwc;
        tDst[i] = (row2 * 66 + wp) * CSTR + chh * 8;
    }

    float tb[4][8];
    auto issueT = [&](int i, int dq) {
        if (tOk[i]) {
            const float* p = x + tSrc[i] + dq * 131072;
#pragma unroll
            for (int u = 0; u < 8; ++u) tb[i][u] = p[u * 4096];
        }
    };
    auto commitT = [&](int i, unsigned short* dst) {
        if (tOk[i]) {
            uint4 pk;
            pk.x = (unsigned)f2h_bits(tb[i][0]) | ((unsigned)f2h_bits(tb[i][1]) << 16);
            pk.y = (unsigned)f2h_bits(tb[i][2]) | ((unsigned)f2h_bits(tb[i][3]) << 16);
            pk.z = (unsigned)f2h_bits(tb[i][4]) | ((unsigned)f2h_bits(tb[i][5]) << 16);
            pk.w = (unsigned)f2h_bits(tb[i][6]) | ((unsigned)f2h_bits(tb[i][7]) << 16);
            *(uint4*)(dst + tDst[i]) = pk;
        }
    };

    const int ph = rw >> 1, eh = rw & 1;
    half8 Aa[3][2];
    uint4 Bb[3][2];
    auto prefA = [&](const unsigned short* buf, int t, int slot) {
        const int kh = t / 3, kw = t % 3;
        const unsigned short* abase =
            buf + (kh * 66 + ph * 32 + (lane & 15) + kw) * CSTR + (lane >> 4) * 8;
#pragma unroll
        for (int mt = 0; mt < 2; ++mt)
            Aa[slot][mt] = *(const half8*)(abase + mt * 16 * CSTR);
    };
    auto prefB = [&](int T9, int slot) {
        const uint4* bp = (const uint4*)wB + (T9 * 4 + eh * 2) * 64 + lane;
#pragma unroll
        for (int nt = 0; nt < 2; ++nt) Bb[slot][nt] = bp[nt * 64];
    };

    f32x4 acc[2][2];
#pragma unroll
    for (int mt = 0; mt < 2; ++mt)
#pragma unroll
        for (int nt = 0; nt < 2; ++nt) acc[mt][nt] = (f32x4){0.f, 0.f, 0.f, 0.f};

    auto mfma_tap = [&](int slot) {
#pragma unroll
        for (int nt = 0; nt < 2; ++nt) {
            half8 bfr;
            __builtin_memcpy(&bfr, &Bb[slot][nt], 16);
#pragma unroll
            for (int mt = 0; mt < 2; ++mt)
                acc[mt][nt] = __builtin_amdgcn_mfma_f32_16x16x32_f16(
                    Aa[slot][mt], bfr, acc[mt][nt], 0, 0, 0);
        }
    };

    __syncthreads();
    issueT(0, 0); issueT(1, 0); issueT(2, 0); issueT(3, 0);
    commitT(0, xs); commitT(1, xs); commitT(2, xs); commitT(3, xs);
    issueT(0, 1); issueT(1, 1); issueT(2, 1); issueT(3, 1);
    prefB(0, 0); prefB(1, 1); prefB(2, 2);
    __syncthreads();

#pragma unroll 1
    for (int q = 0; q < 8; ++q) {
        const unsigned short* cur = xs + (q & 1) * SLAB;
        unsigned short*       nxt = xs + ((q + 1) & 1) * SLAB;
        const int  T0  = q * 9;
        const bool cmt = (q < 7);
        const bool iss = (q < 6);

        prefA(cur, 0, 0); prefA(cur, 1, 1);
        mfma_tap(0); prefB(T0 + 3, 0); prefA(cur, 2, 2);
        mfma_tap(1); prefB(T0 + 4, 1); prefA(cur, 3, 0);
        if (cmt) { commitT(0, nxt); commitT(1, nxt); }
        mfma_tap(2); prefB(T0 + 5, 2); prefA(cur, 4, 1);
        mfma_tap(0); prefB(T0 + 6, 0); prefA(cur, 5, 2);
        if (cmt) { commitT(2, nxt); commitT(3, nxt); }
        mfma_tap(1); prefB(T0 + 7, 1); prefA(cur, 6, 0);
        mfma_tap(2); prefB(T0 + 8, 2); prefA(cur, 7, 1);
        __builtin_amdgcn_sched_barrier(0);
        if (iss) { issueT(0, q + 2); issueT(1, q + 2); issueT(2, q + 2); issueT(3, q + 2); }
        __builtin_amdgcn_sched_barrier(0);
        mfma_tap(0); if (cmt) prefB(T0 + 9, 0);  prefA(cur, 8, 2);
        mfma_tap(1); if (cmt) prefB(T0 + 10, 1);
        mfma_tap(2); if (cmt) prefB(T0 + 11, 2);
        __syncthreads();
    }

    float* scf2 = (float*)xs;
#pragma unroll
    for (int mt = 0; mt < 2; ++mt)
#pragma unroll
        for (int nt = 0; nt < 2; ++nt)
#pragma unroll
            for (int rr = 0; rr < 4; ++rr) {
                float v = acc[mt][nt][rr];
                float s = 1.f / (1.f + __builtin_amdgcn_exp2f(-v * LOG2E));
                int p = ph * 32 + mt * 16 + ((lane >> 4) << 2) + rr;
                int e = eh * 32 + nt * 16 + (lane & 15);
                scf2[p * SSTR + e] = s;
            }
    __syncthreads();

    if (tid < 64) {
        const float* row = scf2 + tid * SSTR;
        float tv[8];
        int   ti[8];
#pragma unroll
        for (int k = 0; k < 8; ++k) { tv[k] = -3.0e38f; ti[k] = 0; }
#pragma unroll
        for (int j4 = 0; j4 < 16; ++j4) {
            f32x4 blkv = *(const f32x4*)(row + j4 * 4);
#pragma unroll
            for (int j = 0; j < 4; ++j) {
                int   e  = j4 * 4 + j;
                float bs = blkv[j] + bias_s[e];
                if (bs > tv[7]) {
                    tv[7] = bs; ti[7] = e;
#pragma unroll
                    for (int k = 7; k > 0; --k) {
                        float fa = tv[k - 1], fb = tv[k];
                        int   ia = ti[k - 1], ib = ti[k];
                        bool  sw = fb > fa;
                        tv[k - 1] = sw ? fb : fa; tv[k] = sw ? fa : fb;
                        ti[k - 1] = sw ? ib : ia; ti[k] = sw ? ia : ib;
                    }
                }
            }
        }
        float u[8], mx = -3.0e38f;
#pragma unroll
        for (int k = 0; k < 8; ++k) { u[k] = tv[k] - bias_s[ti[k]]; mx = fmaxf(mx, u[k]); }
        float ex[8], sum = 0.f;
#pragma unroll
        for (int k = 0; k < 8; ++k) { ex[k] = __builtin_amdgcn_exp2f((u[k] - mx) * LOG2E); sum += ex[k]; }
        float inv = 1.f / sum;

        int obase = b * 32768 + r * 64 + tid;
#pragma unroll
        for (int k = 0; k < 8; ++k) {
            out[obase + k * 4096]          = ex[k] * inv;
            out[524288 + obase + k * 4096] = (float)ti[k];
            atomicAdd(&hist[ti[k]], 1);
        }
    }
    __syncthreads();
    if (tid < 64) atomicAdd(out + 1048576 + tid, (float)hist[tid]);
}

// ---------------------------------------------------------------------------
extern "C" void kernel_launch(void* const* d_in, const int* in_sizes, int n_in,
                              void* d_out, int out_size, void* d_ws, size_t ws_size,
                              hipStream_t stream) {
    const float* x    = (const float*)d_in[0];
    const float* gw   = (const float*)d_in[1];
    const float* bias = (const float*)d_in[2];
    float* out = (float*)d_out;

    if (ws_size >= WS_NEED) {
        _Float16* xT = (_Float16*)d_ws;
        unsigned short* wB = (unsigned short*)((char*)d_ws + XT_BYTES);
        prep_all2<<<PREP_GRID, 256, 0, stream>>>(x, gw, xT, wB, out);
        gate_main6<<<2048, 128, 0, stream>>>(xT, bias, wB, out);
    } else {
        unsigned short* wB = (unsigned short*)d_ws;
        gate_prep<<<72, 256, 0, stream>>>(gw, wB, out);
        gate_main_fb<<<1024, 256, 0, stream>>>(x, bias, wB, out);
    }
}